// Round 3
// baseline (118.202 us; speedup 1.0000x reference)
//
#include <hip/hip_runtime.h>

typedef unsigned int u32;

#define HALF_T 2097152u   // 2048*2048/2
#define NPX 2048

// ---------------- threefry2x32 (JAX-exact, 20 rounds) ----------------
__host__ __device__ inline void tf2x32(u32 k0, u32 k1, u32& x0, u32& x1) {
  const u32 ks2 = k0 ^ k1 ^ 0x1BD11BDAu;
  x0 += k0; x1 += k1;
#define TFR(r) { x0 += x1; x1 = (x1 << (r)) | (x1 >> (32 - (r))); x1 ^= x0; }
  TFR(13) TFR(15) TFR(26) TFR(6)
  x0 += k1;  x1 += ks2 + 1u;
  TFR(17) TFR(29) TFR(16) TFR(24)
  x0 += ks2; x1 += k0 + 2u;
  TFR(13) TFR(15) TFR(26) TFR(6)
  x0 += k0;  x1 += k1 + 3u;
  TFR(17) TFR(29) TFR(16) TFR(24)
  x0 += k1;  x1 += ks2 + 4u;
  TFR(13) TFR(15) TFR(26) TFR(6)
  x0 += ks2; x1 += k0 + 5u;
#undef TFR
}

// Partitionable-threefry random bits for flat index t (size < 2^32 -> hi word 0):
// bits[t] = x0 ^ x1 of threefry2x32(key, (0, t)).
__device__ inline u32 pbits(u32 k0, u32 k1, u32 t) {
  u32 x0 = 0u, x1 = t;
  tf2x32(k0, k1, x0, x1);
  return x0 ^ x1;
}

__device__ inline float bits_to_uniform(u32 bits) {
  return __uint_as_float((bits >> 9) | 0x3F800000u) - 1.0f;
}

// -------- kernel 1: maxpool + noise + store dn + partial min/max --------
template<bool STORE>
__global__ __launch_bounds__(256) void k_pool(const float* __restrict__ coarse,
                                              float* __restrict__ dn,
                                              float* __restrict__ pmin,
                                              float* __restrict__ pmax,
                                              u32 kn0, u32 kn1) {
  float lmin = INFINITY, lmax = -INFINITY;
  const int stride = gridDim.x * 256;
  for (u32 t = blockIdx.x * 256 + threadIdx.x; t < HALF_T; t += stride) {
    const int i = t >> 11, j = t & 2047;   // pool row (first half) / col
    const float2* r0 = (const float2*)(coarse + (size_t)(2*i    ) * 4096);
    const float2* r1 = (const float2*)(coarse + (size_t)(2*i + 1) * 4096);
    float2 a = r0[j], b = r1[j];
    float p0 = fmaxf(fmaxf(a.x, a.y), fmaxf(b.x, b.y));
    const float2* r2 = (const float2*)(coarse + (size_t)(2*i + 2048) * 4096);
    const float2* r3 = (const float2*)(coarse + (size_t)(2*i + 2049) * 4096);
    float2 c = r2[j], d = r3[j];
    float p1 = fmaxf(fmaxf(c.x, c.y), fmaxf(d.x, d.y));
    lmin = fminf(lmin, fminf(p0, p1));
    lmax = fmaxf(lmax, fmaxf(p0, p1));
    if (STORE) {
      dn[t]          = p0 + bits_to_uniform(pbits(kn0, kn1, t));
      dn[t + HALF_T] = p1 + bits_to_uniform(pbits(kn0, kn1, t + HALF_T));
    }
  }
  // wave (64) reduce, then block reduce
  for (int off = 32; off > 0; off >>= 1) {
    lmin = fminf(lmin, __shfl_down(lmin, off, 64));
    lmax = fmaxf(lmax, __shfl_down(lmax, off, 64));
  }
  __shared__ float smin[4], smax[4];
  const int lane = threadIdx.x & 63, wv = threadIdx.x >> 6;
  if (lane == 0) { smin[wv] = lmin; smax[wv] = lmax; }
  __syncthreads();
  if (threadIdx.x == 0) {
    pmin[blockIdx.x] = fminf(fminf(smin[0], smin[1]), fminf(smin[2], smin[3]));
    pmax[blockIdx.x] = fmaxf(fmaxf(smax[0], smax[1]), fmaxf(smax[2], smax[3]));
  }
}

// -------- kernel 1b: final min/max -> thr --------
__global__ __launch_bounds__(256) void k_final(const float* __restrict__ pmin,
                                               const float* __restrict__ pmax,
                                               float* __restrict__ thr, int nblk) {
  float lmin = INFINITY, lmax = -INFINITY;
  for (int i = threadIdx.x; i < nblk; i += 256) {
    lmin = fminf(lmin, pmin[i]);
    lmax = fmaxf(lmax, pmax[i]);
  }
  for (int off = 32; off > 0; off >>= 1) {
    lmin = fminf(lmin, __shfl_down(lmin, off, 64));
    lmax = fmaxf(lmax, __shfl_down(lmax, off, 64));
  }
  __shared__ float smin[4], smax[4];
  const int lane = threadIdx.x & 63, wv = threadIdx.x >> 6;
  if (lane == 0) { smin[wv] = lmin; smax[wv] = lmax; }
  __syncthreads();
  if (threadIdx.x == 0) {
    float gmin = fminf(fminf(smin[0], smin[1]), fminf(smin[2], smin[3]));
    float gmax = fmaxf(fmaxf(smax[0], smax[1]), fmaxf(smax[2], smax[3]));
    thr[0] = (gmax - gmin) / 2048.0f;
  }
}

// -------- adjacency evaluation from an LDS tile --------
// s[lc][lr] = dn[i = cbase-1+lc][j = rbase-1+lr]; thread center at lc=tx+1, lr=ty+1.
// c plays the role of i (out col), rr the role of j (out row).
__device__ inline bool adj_eval(const float s[34][35], int tx, int ty,
                                int c, int rr, float thr) {
  const float ctr = s[tx+1][ty+1];
  const bool cge1 = (c  >= 1),    cle = (c  <= NPX - 2);
  const bool rge1 = (rr >= 1),    rle = (rr <= NPX - 2);
  bool a = false;
  if (cge1 && rge1)                    a |= (fabsf(s[tx  ][ty  ] - ctr) <= thr); // (dx=-1,dy=-1): d[i-1,j-1]
  if (cge1 && cle && rge1 && rle)      a |= (fabsf(s[tx+2][ty  ] - ctr) <= thr); // (dx=-1,dy=+1): d[i+1,j-1]
  if (cge1 && rle)                     a |= (fabsf(s[tx  ][ty+2] - ctr) <= thr); // (dx=+1,dy=-1): d[i-1,j+1]
  if (cle  && rle)                     a |= (fabsf(s[tx+2][ty+2] - ctr) <= thr); // (dx=+1,dy=+1): d[i+1,j+1]
  return a;
}

// -------- kernel 2 (stored path): adjacency + dropout; OUTPUT IS INT32 --------
__global__ __launch_bounds__(1024) void k_graph(const float* __restrict__ dn,
                                                const float* __restrict__ thrp,
                                                int* __restrict__ out,
                                                u32 kd0, u32 kd1) {
  __shared__ float s0[34][35];
  __shared__ float s1[34][35];
  const float thr = *thrp;
  const int c0 = blockIdx.x * 32, r0 = blockIdx.y * 32;
  const int tid = threadIdx.y * 32 + threadIdx.x;
  for (int idx = tid; idx < 34 * 34; idx += 1024) {
    const int lc = idx / 34, lr = idx - lc * 34;
    const int c = c0 - 1 + lc;        // dn row index (i)
    const int r = r0 - 1 + lr;        // dn col index (j), tile0
    float v0 = 0.f, v1 = 0.f;
    if ((unsigned)c < (unsigned)NPX) {
      if ((unsigned)r < (unsigned)NPX)          v0 = dn[c * NPX + r];
      const int r2 = r + 1024;
      if ((unsigned)r2 < (unsigned)NPX)         v1 = dn[c * NPX + r2];
    }
    s0[lc][lr] = v0;
    s1[lc][lr] = v1;
  }
  __syncthreads();
  const int tx = threadIdx.x, ty = threadIdx.y;
  const int c = c0 + tx, r = r0 + ty;          // out col / out row (first tile)
  const bool adj0 = adj_eval(s0, tx, ty, c, r,        thr);
  const bool adj1 = adj_eval(s1, tx, ty, c, r + 1024, thr);
  const u32 t0 = (u32)(r * NPX + c);
  // bernoulli(0.5): uniform < 0.5  <=>  top bit of bits == 0
  const bool keep0 = !(pbits(kd0, kd1, t0)          >> 31);
  const bool keep1 = !(pbits(kd0, kd1, t0 + HALF_T) >> 31);
  out[(size_t)r * NPX + c]          = (adj0 && keep0) ? 1 : 0;
  out[(size_t)(r + 1024) * NPX + c] = (adj1 && keep1) ? 1 : 0;
}

// -------- fused dn recompute (fallback when ws too small for dn) --------
__device__ inline float dn_compute(const float* __restrict__ coarse,
                                   int i, int j, u32 kn0, u32 kn1) {
  const float2* r0 = (const float2*)(coarse + (size_t)(2*i    ) * 4096);
  const float2* r1 = (const float2*)(coarse + (size_t)(2*i + 1) * 4096);
  float2 a = r0[j], b = r1[j];
  float p = fmaxf(fmaxf(a.x, a.y), fmaxf(b.x, b.y));
  return p + bits_to_uniform(pbits(kn0, kn1, (u32)(i * NPX + j)));
}

__global__ __launch_bounds__(1024) void k_graph_fused(const float* __restrict__ coarse,
                                                      const float* __restrict__ thrp,
                                                      int* __restrict__ out,
                                                      u32 kn0, u32 kn1, u32 kd0, u32 kd1) {
  __shared__ float s0[34][35];
  __shared__ float s1[34][35];
  const float thr = *thrp;
  const int c0 = blockIdx.x * 32, r0 = blockIdx.y * 32;
  const int tid = threadIdx.y * 32 + threadIdx.x;
  for (int idx = tid; idx < 34 * 34; idx += 1024) {
    const int lc = idx / 34, lr = idx - lc * 34;
    const int c = c0 - 1 + lc;
    const int r = r0 - 1 + lr;
    float v0 = 0.f, v1 = 0.f;
    if ((unsigned)c < (unsigned)NPX) {
      if ((unsigned)r < (unsigned)NPX)      v0 = dn_compute(coarse, c, r, kn0, kn1);
      const int r2 = r + 1024;
      if ((unsigned)r2 < (unsigned)NPX)     v1 = dn_compute(coarse, c, r2, kn0, kn1);
    }
    s0[lc][lr] = v0;
    s1[lc][lr] = v1;
  }
  __syncthreads();
  const int tx = threadIdx.x, ty = threadIdx.y;
  const int c = c0 + tx, r = r0 + ty;
  const bool adj0 = adj_eval(s0, tx, ty, c, r,        thr);
  const bool adj1 = adj_eval(s1, tx, ty, c, r + 1024, thr);
  const u32 t0 = (u32)(r * NPX + c);
  const bool keep0 = !(pbits(kd0, kd1, t0)          >> 31);
  const bool keep1 = !(pbits(kd0, kd1, t0 + HALF_T) >> 31);
  out[(size_t)r * NPX + c]          = (adj0 && keep0) ? 1 : 0;
  out[(size_t)(r + 1024) * NPX + c] = (adj1 && keep1) ? 1 : 0;
}

// ---------------- launch ----------------
extern "C" void kernel_launch(void* const* d_in, const int* in_sizes, int n_in,
                              void* d_out, int out_size, void* d_ws, size_t ws_size,
                              hipStream_t stream) {
  const float* coarse = (const float*)d_in[0];
  int* out = (int*)d_out;

  // jax.random.split under threefry_partitionable (modern default), "foldlike":
  // keys[i] = full output pair of threefry2x32(key=(0,1), counts=(hi=0, lo=i)).
  u32 a0 = 0u, a1 = 0u; tf2x32(0u, 1u, a0, a1);   // k_noise = tf(key, (0,0))
  u32 b0 = 0u, b1 = 1u; tf2x32(0u, 1u, b0, b1);   // k_drop  = tf(key, (0,1))
  const u32 kn0 = a0, kn1 = a1, kd0 = b0, kd1 = b1;

  char* ws = (char*)d_ws;
  float* thr  = (float*)ws;                   // 4 B
  float* pmin = (float*)(ws + 64);            // 2048 floats
  float* pmax = (float*)(ws + 64 + 8192);     // 2048 floats
  const size_t dn_off = 32768;
  const size_t dn_bytes = (size_t)NPX * NPX * sizeof(float);
  const bool stored = ws_size >= dn_off + dn_bytes;

  if (stored) {
    float* dn = (float*)(ws + dn_off);
    k_pool<true><<<2048, 256, 0, stream>>>(coarse, dn, pmin, pmax, kn0, kn1);
    k_final<<<1, 256, 0, stream>>>(pmin, pmax, thr, 2048);
    k_graph<<<dim3(64, 32), dim3(32, 32), 0, stream>>>(dn, thr, out, kd0, kd1);
  } else {
    k_pool<false><<<2048, 256, 0, stream>>>(coarse, nullptr, pmin, pmax, kn0, kn1);
    k_final<<<1, 256, 0, stream>>>(pmin, pmax, thr, 2048);
    k_graph_fused<<<dim3(64, 32), dim3(32, 32), 0, stream>>>(coarse, thr, out,
                                                             kn0, kn1, kd0, kd1);
  }
}

// Round 4
// 117.731 us; speedup vs baseline: 1.0040x; 1.0040x over previous
//
#include <hip/hip_runtime.h>

typedef unsigned int u32;

#define HALF_T 2097152u   // 2048*2048/2
#define NPX 2048
#define NPOOL_BLOCKS 4096

// ---------------- threefry2x32 (JAX-exact, 20 rounds) ----------------
__host__ __device__ inline void tf2x32(u32 k0, u32 k1, u32& x0, u32& x1) {
  const u32 ks2 = k0 ^ k1 ^ 0x1BD11BDAu;
  x0 += k0; x1 += k1;
#define TFR(r) { x0 += x1; x1 = (x1 << (r)) | (x1 >> (32 - (r))); x1 ^= x0; }
  TFR(13) TFR(15) TFR(26) TFR(6)
  x0 += k1;  x1 += ks2 + 1u;
  TFR(17) TFR(29) TFR(16) TFR(24)
  x0 += ks2; x1 += k0 + 2u;
  TFR(13) TFR(15) TFR(26) TFR(6)
  x0 += k0;  x1 += k1 + 3u;
  TFR(17) TFR(29) TFR(16) TFR(24)
  x0 += k1;  x1 += ks2 + 4u;
  TFR(13) TFR(15) TFR(26) TFR(6)
  x0 += ks2; x1 += k0 + 5u;
#undef TFR
}

// Partitionable-threefry random bits for flat index t (size < 2^32 -> hi word 0):
// bits[t] = x0 ^ x1 of threefry2x32(key, (0, t)).
__device__ inline u32 pbits(u32 k0, u32 k1, u32 t) {
  u32 x0 = 0u, x1 = t;
  tf2x32(k0, k1, x0, x1);
  return x0 ^ x1;
}

__device__ inline float bits_to_uniform(u32 bits) {
  return __uint_as_float((bits >> 9) | 0x3F800000u) - 1.0f;
}

// -------- kernel 1: maxpool + noise + store dn (float2) + partial min/max --------
// 4096 blocks x 256 threads; thread g handles pool rows (i, i+1024), cols (2jj, 2jj+1).
__global__ __launch_bounds__(256) void k_pool(const float* __restrict__ coarse,
                                              float2* __restrict__ dn2,
                                              float* __restrict__ pmin,
                                              float* __restrict__ pmax,
                                              u32 kn0, u32 kn1) {
  const u32 g = blockIdx.x * 256 + threadIdx.x;   // [0, 1048576)
  const int i  = g >> 10;                         // pool row in [0,1024)
  const int jj = g & 1023;                        // float4 col index

  const float4* r0 = (const float4*)(coarse + (size_t)(2*i       ) * 4096);
  const float4* r1 = (const float4*)(coarse + (size_t)(2*i + 1   ) * 4096);
  const float4* r2 = (const float4*)(coarse + (size_t)(2*i + 2048) * 4096);
  const float4* r3 = (const float4*)(coarse + (size_t)(2*i + 2049) * 4096);
  const float4 a = r0[jj], b = r1[jj], c = r2[jj], d = r3[jj];

  const float p0a = fmaxf(fmaxf(a.x, a.y), fmaxf(b.x, b.y));
  const float p0b = fmaxf(fmaxf(a.z, a.w), fmaxf(b.z, b.w));
  const float p1a = fmaxf(fmaxf(c.x, c.y), fmaxf(d.x, d.y));
  const float p1b = fmaxf(fmaxf(c.z, c.w), fmaxf(d.z, d.w));

  float lmin = fminf(fminf(p0a, p0b), fminf(p1a, p1b));
  float lmax = fmaxf(fmaxf(p0a, p0b), fmaxf(p1a, p1b));

  const u32 t0 = (u32)i * 2048u + 2u * (u32)jj;
  const u32 t2 = t0 + HALF_T;
  dn2[(size_t)i * 1024 + jj] =
      make_float2(p0a + bits_to_uniform(pbits(kn0, kn1, t0)),
                  p0b + bits_to_uniform(pbits(kn0, kn1, t0 + 1u)));
  dn2[(size_t)(i + 1024) * 1024 + jj] =
      make_float2(p1a + bits_to_uniform(pbits(kn0, kn1, t2)),
                  p1b + bits_to_uniform(pbits(kn0, kn1, t2 + 1u)));

  // wave (64) reduce, then block reduce
  for (int off = 32; off > 0; off >>= 1) {
    lmin = fminf(lmin, __shfl_down(lmin, off, 64));
    lmax = fmaxf(lmax, __shfl_down(lmax, off, 64));
  }
  __shared__ float smin[4], smax[4];
  const int lane = threadIdx.x & 63, wv = threadIdx.x >> 6;
  if (lane == 0) { smin[wv] = lmin; smax[wv] = lmax; }
  __syncthreads();
  if (threadIdx.x == 0) {
    pmin[blockIdx.x] = fminf(fminf(smin[0], smin[1]), fminf(smin[2], smin[3]));
    pmax[blockIdx.x] = fmaxf(fmaxf(smax[0], smax[1]), fmaxf(smax[2], smax[3]));
  }
}

// -------- per-block redundant final reduce (partials sit in L2) --------
__device__ inline float block_thr(const float* __restrict__ pmin,
                                  const float* __restrict__ pmax,
                                  int tid) {
  __shared__ float smin[16], smax[16], sthr;
  float lmin = INFINITY, lmax = -INFINITY;
#pragma unroll
  for (int k = 0; k < NPOOL_BLOCKS; k += 1024) {
    lmin = fminf(lmin, pmin[tid + k]);
    lmax = fmaxf(lmax, pmax[tid + k]);
  }
  for (int off = 32; off > 0; off >>= 1) {
    lmin = fminf(lmin, __shfl_down(lmin, off, 64));
    lmax = fmaxf(lmax, __shfl_down(lmax, off, 64));
  }
  const int lane = tid & 63, wv = tid >> 6;
  if (lane == 0) { smin[wv] = lmin; smax[wv] = lmax; }
  __syncthreads();
  if (tid == 0) {
    float gmin = smin[0], gmax = smax[0];
#pragma unroll
    for (int w = 1; w < 16; ++w) {
      gmin = fminf(gmin, smin[w]);
      gmax = fmaxf(gmax, smax[w]);
    }
    sthr = (gmax - gmin) / 2048.0f;
  }
  __syncthreads();
  return sthr;
}

// -------- adjacency evaluation from an LDS tile --------
// s[lc][lr] = dn[i = cbase-1+lc][j = rbase-1+lr]; thread center at lc=tx+1, lr=ty+1.
__device__ inline bool adj_eval(const float s[34][35], int tx, int ty,
                                int c, int rr, float thr) {
  const float ctr = s[tx+1][ty+1];
  const bool cge1 = (c  >= 1),    cle = (c  <= NPX - 2);
  const bool rge1 = (rr >= 1),    rle = (rr <= NPX - 2);
  bool a = false;
  if (cge1 && rge1)                    a |= (fabsf(s[tx  ][ty  ] - ctr) <= thr); // d[i-1,j-1]
  if (cge1 && cle && rge1 && rle)      a |= (fabsf(s[tx+2][ty  ] - ctr) <= thr); // d[i+1,j-1]
  if (cge1 && rle)                     a |= (fabsf(s[tx  ][ty+2] - ctr) <= thr); // d[i-1,j+1]
  if (cle  && rle)                     a |= (fabsf(s[tx+2][ty+2] - ctr) <= thr); // d[i+1,j+1]
  return a;
}

// -------- kernel 2: thr reduce + adjacency + dropout; OUTPUT IS INT32 --------
__global__ __launch_bounds__(1024) void k_graph(const float* __restrict__ dn,
                                                const float* __restrict__ pmin,
                                                const float* __restrict__ pmax,
                                                int* __restrict__ out,
                                                u32 kd0, u32 kd1) {
  __shared__ float s0[34][35];
  __shared__ float s1[34][35];
  const int tid = threadIdx.y * 32 + threadIdx.x;
  const float thr = block_thr(pmin, pmax, tid);

  const int c0 = blockIdx.x * 32, r0 = blockIdx.y * 32;
  for (int idx = tid; idx < 34 * 34; idx += 1024) {
    const int lc = idx / 34, lr = idx - lc * 34;
    const int c = c0 - 1 + lc;        // dn row index (i)
    const int r = r0 - 1 + lr;        // dn col index (j), tile0
    float v0 = 0.f, v1 = 0.f;
    if ((unsigned)c < (unsigned)NPX) {
      if ((unsigned)r < (unsigned)NPX)          v0 = dn[c * NPX + r];
      const int r2 = r + 1024;
      if ((unsigned)r2 < (unsigned)NPX)         v1 = dn[c * NPX + r2];
    }
    s0[lc][lr] = v0;
    s1[lc][lr] = v1;
  }
  __syncthreads();
  const int tx = threadIdx.x, ty = threadIdx.y;
  const int c = c0 + tx, r = r0 + ty;          // out col / out row (first tile)
  const bool adj0 = adj_eval(s0, tx, ty, c, r,        thr);
  const bool adj1 = adj_eval(s1, tx, ty, c, r + 1024, thr);
  const u32 t0 = (u32)(r * NPX + c);
  // bernoulli(0.5): uniform < 0.5  <=>  top bit of bits == 0
  const bool keep0 = !(pbits(kd0, kd1, t0)          >> 31);
  const bool keep1 = !(pbits(kd0, kd1, t0 + HALF_T) >> 31);
  out[(size_t)r * NPX + c]          = (adj0 && keep0) ? 1 : 0;
  out[(size_t)(r + 1024) * NPX + c] = (adj1 && keep1) ? 1 : 0;
}

// -------- fallback (ws too small for dn): minmax-only pool + fused recompute --------
__global__ __launch_bounds__(256) void k_pool_nostore(const float* __restrict__ coarse,
                                                      float* __restrict__ pmin,
                                                      float* __restrict__ pmax) {
  const u32 g = blockIdx.x * 256 + threadIdx.x;
  const int i  = g >> 10;
  const int jj = g & 1023;
  const float4* r0 = (const float4*)(coarse + (size_t)(2*i       ) * 4096);
  const float4* r1 = (const float4*)(coarse + (size_t)(2*i + 1   ) * 4096);
  const float4* r2 = (const float4*)(coarse + (size_t)(2*i + 2048) * 4096);
  const float4* r3 = (const float4*)(coarse + (size_t)(2*i + 2049) * 4096);
  const float4 a = r0[jj], b = r1[jj], c = r2[jj], d = r3[jj];
  float lmin = fminf(fminf(fmaxf(fmaxf(a.x,a.y),fmaxf(b.x,b.y)),
                           fmaxf(fmaxf(a.z,a.w),fmaxf(b.z,b.w))),
                     fminf(fmaxf(fmaxf(c.x,c.y),fmaxf(d.x,d.y)),
                           fmaxf(fmaxf(c.z,c.w),fmaxf(d.z,d.w))));
  float lmax = fmaxf(fmaxf(fmaxf(fmaxf(a.x,a.y),fmaxf(b.x,b.y)),
                           fmaxf(fmaxf(a.z,a.w),fmaxf(b.z,b.w))),
                     fmaxf(fmaxf(fmaxf(c.x,c.y),fmaxf(d.x,d.y)),
                           fmaxf(fmaxf(c.z,c.w),fmaxf(d.z,d.w))));
  for (int off = 32; off > 0; off >>= 1) {
    lmin = fminf(lmin, __shfl_down(lmin, off, 64));
    lmax = fmaxf(lmax, __shfl_down(lmax, off, 64));
  }
  __shared__ float smin[4], smax[4];
  const int lane = threadIdx.x & 63, wv = threadIdx.x >> 6;
  if (lane == 0) { smin[wv] = lmin; smax[wv] = lmax; }
  __syncthreads();
  if (threadIdx.x == 0) {
    pmin[blockIdx.x] = fminf(fminf(smin[0], smin[1]), fminf(smin[2], smin[3]));
    pmax[blockIdx.x] = fmaxf(fmaxf(smax[0], smax[1]), fmaxf(smax[2], smax[3]));
  }
}

__device__ inline float dn_compute(const float* __restrict__ coarse,
                                   int i, int j, u32 kn0, u32 kn1) {
  const float2* r0 = (const float2*)(coarse + (size_t)(2*i    ) * 4096);
  const float2* r1 = (const float2*)(coarse + (size_t)(2*i + 1) * 4096);
  float2 a = r0[j], b = r1[j];
  float p = fmaxf(fmaxf(a.x, a.y), fmaxf(b.x, b.y));
  return p + bits_to_uniform(pbits(kn0, kn1, (u32)(i * NPX + j)));
}

__global__ __launch_bounds__(1024) void k_graph_fused(const float* __restrict__ coarse,
                                                      const float* __restrict__ pmin,
                                                      const float* __restrict__ pmax,
                                                      int* __restrict__ out,
                                                      u32 kn0, u32 kn1, u32 kd0, u32 kd1) {
  __shared__ float s0[34][35];
  __shared__ float s1[34][35];
  const int tid = threadIdx.y * 32 + threadIdx.x;
  const float thr = block_thr(pmin, pmax, tid);
  const int c0 = blockIdx.x * 32, r0 = blockIdx.y * 32;
  for (int idx = tid; idx < 34 * 34; idx += 1024) {
    const int lc = idx / 34, lr = idx - lc * 34;
    const int c = c0 - 1 + lc;
    const int r = r0 - 1 + lr;
    float v0 = 0.f, v1 = 0.f;
    if ((unsigned)c < (unsigned)NPX) {
      if ((unsigned)r < (unsigned)NPX)      v0 = dn_compute(coarse, c, r, kn0, kn1);
      const int r2 = r + 1024;
      if ((unsigned)r2 < (unsigned)NPX)     v1 = dn_compute(coarse, c, r2, kn0, kn1);
    }
    s0[lc][lr] = v0;
    s1[lc][lr] = v1;
  }
  __syncthreads();
  const int tx = threadIdx.x, ty = threadIdx.y;
  const int c = c0 + tx, r = r0 + ty;
  const bool adj0 = adj_eval(s0, tx, ty, c, r,        thr);
  const bool adj1 = adj_eval(s1, tx, ty, c, r + 1024, thr);
  const u32 t0 = (u32)(r * NPX + c);
  const bool keep0 = !(pbits(kd0, kd1, t0)          >> 31);
  const bool keep1 = !(pbits(kd0, kd1, t0 + HALF_T) >> 31);
  out[(size_t)r * NPX + c]          = (adj0 && keep0) ? 1 : 0;
  out[(size_t)(r + 1024) * NPX + c] = (adj1 && keep1) ? 1 : 0;
}

// ---------------- launch ----------------
extern "C" void kernel_launch(void* const* d_in, const int* in_sizes, int n_in,
                              void* d_out, int out_size, void* d_ws, size_t ws_size,
                              hipStream_t stream) {
  const float* coarse = (const float*)d_in[0];
  int* out = (int*)d_out;

  // jax.random.split under threefry_partitionable (modern default), "foldlike":
  // keys[i] = full output pair of threefry2x32(key=(0,1), counts=(hi=0, lo=i)).
  u32 a0 = 0u, a1 = 0u; tf2x32(0u, 1u, a0, a1);   // k_noise = tf(key, (0,0))
  u32 b0 = 0u, b1 = 1u; tf2x32(0u, 1u, b0, b1);   // k_drop  = tf(key, (0,1))
  const u32 kn0 = a0, kn1 = a1, kd0 = b0, kd1 = b1;

  char* ws = (char*)d_ws;
  float* pmin = (float*)ws;                       // 4096 floats
  float* pmax = (float*)(ws + 16384);             // 4096 floats
  const size_t dn_off = 32768;
  const size_t dn_bytes = (size_t)NPX * NPX * sizeof(float);
  const bool stored = ws_size >= dn_off + dn_bytes;

  if (stored) {
    float* dn = (float*)(ws + dn_off);
    k_pool<<<NPOOL_BLOCKS, 256, 0, stream>>>(coarse, (float2*)dn, pmin, pmax, kn0, kn1);
    k_graph<<<dim3(64, 32), dim3(32, 32), 0, stream>>>(dn, pmin, pmax, out, kd0, kd1);
  } else {
    k_pool_nostore<<<NPOOL_BLOCKS, 256, 0, stream>>>(coarse, pmin, pmax);
    k_graph_fused<<<dim3(64, 32), dim3(32, 32), 0, stream>>>(coarse, pmin, pmax, out,
                                                             kn0, kn1, kd0, kd1);
  }
}